// Round 6
// baseline (324.454 us; speedup 1.0000x reference)
//
#include <hip/hip_runtime.h>
#include <cmath>

#define BINS 10
#define EDGE_TOP (1.0f + 1e-6f)
#define BLK 256
#define MAXJ 16            // float4-groups/thread cached as codes in LDS (8 KB)
#define MAXG 2048
#define READY 0x5A5A5A5Au  // marker: != 0x00000000 and != 0xAAAAAAAA (poison)

// Classify via native v_exp_f32. Near-bin-boundary values recomputed with
// double-precision exp so the fp32 result matches numpy's fp32 exp.
// __expf rel err <= ~4e-7 -> disagreement band <= 8e-6 in g*10 space;
// margin 4e-5 is 5x safe. Proven R1-R5: absmax 7.8e-3 vs threshold 0.385.
__device__ __forceinline__ void ghm_classify_fast(float p, int& bin, bool& lt_top) {
    float ef  = __expf(-p);
    float g   = fabsf(ef - 1.0f);
    float g10 = g * 10.0f;
    int   b   = (int)g10;          // g >= 0, trunc == floor
    float fb  = (float)b;
    bool hazard = (g10 - fb < 4e-5f) || (fb + 1.0f - g10 < 4e-5f) ||
                  (fabsf(g - EDGE_TOP) < 4e-6f);
    if (hazard) {
        double ed = exp(-(double)p);
        float ef2 = (float)ed;     // ~correctly-rounded fp32 exp
        g   = fabsf(ef2 - 1.0f);
        g10 = g * 10.0f;
        b   = (int)g10;
    }
    bin    = (b < 9) ? b : 9;
    lt_top = (g < EDGE_TOP);
}

// Process 4 elements: update packed histogram (2 x u64, 12-bit fields,
// safe to 4095 elems/thread) + valid count; return 4x4-bit code word.
__device__ __forceinline__ unsigned int ghm_p4(float4 P, float4 W,
    unsigned long long& h0, unsigned long long& h1, unsigned int& vcnt)
{
    float ps[4] = {P.x, P.y, P.z, P.w};
    float ws[4] = {W.x, W.y, W.z, W.w};
    unsigned int code = 0u;
#pragma unroll
    for (int k = 0; k < 4; ++k) {
        bool valid = ws[k] > 0.0f;
        vcnt += valid ? 1u : 0u;
        int bin; bool lt;
        ghm_classify_fast(ps[k], bin, lt);
        bool ib = valid && lt;
        bool hi = bin >= 5;
        unsigned int sh = (unsigned int)((hi ? bin - 5 : bin) * 12);
        unsigned long long inc = ib ? (1ull << sh) : 0ull;
        h0 += hi ? 0ull : inc;
        h1 += hi ? inc : 0ull;
        code |= (ib ? (unsigned int)bin : 15u) << (k * 4);
    }
    return code;
}

// Recompute a code word (phase-2 LDS-overflow fallback; not hit at G=1024).
__device__ __forceinline__ unsigned int ghm_code4(float4 P, float4 W)
{
    float ps[4] = {P.x, P.y, P.z, P.w};
    float ws[4] = {W.x, W.y, W.z, W.w};
    unsigned int code = 0u;
#pragma unroll
    for (int k = 0; k < 4; ++k) {
        int bin; bool lt;
        ghm_classify_fast(ps[k], bin, lt);
        bool ib = (ws[k] > 0.0f) && lt;
        code |= (ib ? (unsigned int)bin : 15u) << (k * 4);
    }
    return code;
}

#define AGENT __HIP_MEMORY_SCOPE_AGENT

// Single fused cooperative kernel with a hand-rolled flush-free grid barrier:
//  phase 1: 4-deep pipelined classify; codes -> LDS; block reduce; publish
//           11 partials + READY marker (agent-scope atomics bypass the
//           non-coherent per-XCD L2s -> no cg::sync cache flushes needed).
//  block 0: poll markers, reduce partials, build 16-entry weight table
//           (reference fp32 op order), publish + flag. Others poll flag.
//  phase 2: out = wtab[code] * pred (pred re-read, LLC-warm).
__global__ __launch_bounds__(BLK, 6) void ghm_fused(
    const float* __restrict__ pred, const float* __restrict__ lw,
    unsigned int* __restrict__ ws, float* __restrict__ out, int n)
{
    __shared__ unsigned short lds_codes[MAXJ * BLK];  // 8 KB
    __shared__ unsigned int sc[16];
    __shared__ float wtab[16];

    unsigned int* part  = ws;                  // [MAXG][16]: 0..10 counts, 11 marker
    unsigned int* wtabg = ws + MAXG * 16;      // 16 words (float bits)
    unsigned int* flag  = ws + MAXG * 16 + 16; // 1 word

    const float4* p4 = (const float4*)pred;
    const float4* w4 = (const float4*)lw;
    const int n4 = n >> 2;
    const int S  = gridDim.x * BLK;
    const int t0 = blockIdx.x * BLK + threadIdx.x;
    const int G  = gridDim.x;

    unsigned long long h0 = 0ull, h1 = 0ull;
    unsigned int vcnt = 0u;

    // ---- phase 1: 4-deep rotating prefetch pipeline ----
    {
        float4 A0 = {0,0,0,0}, A1 = A0, A2 = A0, A3 = A0;
        float4 B0 = A0, B1 = A0, B2 = A0, B3 = A0;
        if (t0         < n4) { A0 = p4[t0];         B0 = w4[t0]; }
        if (t0 + S     < n4) { A1 = p4[t0 + S];     B1 = w4[t0 + S]; }
        if (t0 + 2 * S < n4) { A2 = p4[t0 + 2 * S]; B2 = w4[t0 + 2 * S]; }
        if (t0 + 3 * S < n4) { A3 = p4[t0 + 3 * S]; B3 = w4[t0 + 3 * S]; }

        int i = t0, j = 0;
        while (i < n4) {
            {
                float4 P = A0, W = B0;
                int nxt = i + 4 * S;
                if (nxt < n4) { A0 = p4[nxt]; B0 = w4[nxt]; }
                unsigned int code = ghm_p4(P, W, h0, h1, vcnt);
                if (j < MAXJ) lds_codes[j * BLK + threadIdx.x] = (unsigned short)code;
            }
            if (i + S < n4) {
                float4 P = A1, W = B1;
                int nxt = i + 5 * S;
                if (nxt < n4) { A1 = p4[nxt]; B1 = w4[nxt]; }
                unsigned int code = ghm_p4(P, W, h0, h1, vcnt);
                if (j + 1 < MAXJ) lds_codes[(j + 1) * BLK + threadIdx.x] = (unsigned short)code;
            }
            if (i + 2 * S < n4) {
                float4 P = A2, W = B2;
                int nxt = i + 6 * S;
                if (nxt < n4) { A2 = p4[nxt]; B2 = w4[nxt]; }
                unsigned int code = ghm_p4(P, W, h0, h1, vcnt);
                if (j + 2 < MAXJ) lds_codes[(j + 2) * BLK + threadIdx.x] = (unsigned short)code;
            }
            if (i + 3 * S < n4) {
                float4 P = A3, W = B3;
                int nxt = i + 7 * S;
                if (nxt < n4) { A3 = p4[nxt]; B3 = w4[nxt]; }
                unsigned int code = ghm_p4(P, W, h0, h1, vcnt);
                if (j + 3 < MAXJ) lds_codes[(j + 3) * BLK + threadIdx.x] = (unsigned short)code;
            }
            i += 4 * S; j += 4;
        }
        // scalar tail (n % 4): counts only (phase 2 writes these directly)
        if (t0 == 0) {
            for (int t = n4 << 2; t < n; ++t) {
                bool valid = lw[t] > 0.0f;
                vcnt += valid ? 1u : 0u;
                int bin; bool lt;
                ghm_classify_fast(pred[t], bin, lt);
                if (valid && lt) {
                    if (bin >= 5) h1 += 1ull << ((bin - 5) * 12);
                    else          h0 += 1ull << (bin * 12);
                }
            }
        }
    }

    // ---- block reduce -> publish partials + READY marker ----
    if (threadIdx.x < 16) sc[threadIdx.x] = 0u;
    __syncthreads();
    {
        unsigned int vals[BINS + 1];
#pragma unroll
        for (int b = 0; b < 5; ++b) vals[b]     = (unsigned int)((h0 >> (12 * b)) & 4095ull);
#pragma unroll
        for (int b = 0; b < 5; ++b) vals[5 + b] = (unsigned int)((h1 >> (12 * b)) & 4095ull);
        vals[BINS] = vcnt;
#pragma unroll
        for (int b = 0; b <= BINS; ++b) {
            unsigned int v = vals[b];
#pragma unroll
            for (int off = 32; off > 0; off >>= 1)
                v += __shfl_down(v, off, 64);
            if ((threadIdx.x & 63) == 0) atomicAdd(&sc[b], v);
        }
    }
    __syncthreads();
    if (threadIdx.x < BINS + 1)
        __hip_atomic_store(&part[(unsigned)blockIdx.x * 16u + threadIdx.x],
                           sc[threadIdx.x], __ATOMIC_RELAXED, AGENT);
    __syncthreads();  // drains vmcnt -> counts globally visible before marker
    if (threadIdx.x == 0)
        __hip_atomic_store(&part[(unsigned)blockIdx.x * 16u + 11], READY,
                           __ATOMIC_RELEASE, AGENT);

    // ---- barrier + finalize ----
    if (blockIdx.x == 0) {
        if (threadIdx.x < 16) sc[threadIdx.x] = 0u;
        __syncthreads();
        unsigned int acc[BINS + 1];
#pragma unroll
        for (int b = 0; b <= BINS; ++b) acc[b] = 0u;
        for (int b = threadIdx.x; b < G; b += BLK) {
            while (__hip_atomic_load(&part[(unsigned)b * 16u + 11],
                                     __ATOMIC_ACQUIRE, AGENT) != READY)
                __builtin_amdgcn_s_sleep(2);
#pragma unroll
            for (int jj = 0; jj <= BINS; ++jj)
                acc[jj] += __hip_atomic_load(&part[(unsigned)b * 16u + jj],
                                             __ATOMIC_RELAXED, AGENT);
        }
#pragma unroll
        for (int b = 0; b <= BINS; ++b) {
            unsigned int v = acc[b];
#pragma unroll
            for (int off = 32; off > 0; off >>= 1)
                v += __shfl_down(v, off, 64);
            if ((threadIdx.x & 63) == 0) atomicAdd(&sc[b], v);
        }
        __syncthreads();
        // every wave computes the same weights from sc[] (wave-uniform)
        const int lane = threadIdx.x & 63;
        unsigned int cv = sc[lane < 11 ? lane : 10];
        float totf = fmaxf((float)__shfl((int)cv, 10, 64), 1.0f);
        unsigned long long nem = __ballot(lane < 10 && cv > 0u);
        int nne = __popcll(nem);
        float nf = fmaxf((float)nne, 1.0f);
        float wfl = 0.0f;
        if (lane < 10 && cv > 0u) {
            wfl = totf / (float)cv;        // tot / counts[b]
            if (nne > 0) wfl = wfl / nf;   // / n_nonempty (reference op order)
        }
        if (threadIdx.x < 16) {
            wtab[threadIdx.x] = wfl;       // lanes 10..15 -> 0.0 (sentinel)
            __hip_atomic_store(&wtabg[threadIdx.x], __float_as_uint(wfl),
                               __ATOMIC_RELAXED, AGENT);
        }
        __syncthreads();  // drains vmcnt -> wtabg visible before flag
        if (threadIdx.x == 0)
            __hip_atomic_store(flag, READY, __ATOMIC_RELEASE, AGENT);
        __syncthreads();
    } else {
        if (threadIdx.x == 0) {
            while (__hip_atomic_load(flag, __ATOMIC_ACQUIRE, AGENT) != READY)
                __builtin_amdgcn_s_sleep(8);
        }
        __syncthreads();
        if (threadIdx.x < 16)
            wtab[threadIdx.x] = __uint_as_float(
                __hip_atomic_load(&wtabg[threadIdx.x], __ATOMIC_RELAXED, AGENT));
        __syncthreads();
    }

    // ---- phase 2: out = wtab[code] * pred (4-deep pipeline) ----
    {
        float4 A0 = {0,0,0,0}, A1 = A0, A2 = A0, A3 = A0;
        if (t0         < n4) A0 = p4[t0];
        if (t0 + S     < n4) A1 = p4[t0 + S];
        if (t0 + 2 * S < n4) A2 = p4[t0 + 2 * S];
        if (t0 + 3 * S < n4) A3 = p4[t0 + 3 * S];

        int i = t0, j = 0;
        while (i < n4) {
            {
                float4 P = A0;
                int nxt = i + 4 * S;
                if (nxt < n4) A0 = p4[nxt];
                unsigned int code = (j < MAXJ)
                    ? (unsigned int)lds_codes[j * BLK + threadIdx.x]
                    : ghm_code4(P, w4[i]);
                float4 O;
                O.x = wtab[code & 15u] * P.x;
                O.y = wtab[(code >> 4) & 15u] * P.y;
                O.z = wtab[(code >> 8) & 15u] * P.z;
                O.w = wtab[(code >> 12) & 15u] * P.w;
                ((float4*)out)[i] = O;
            }
            if (i + S < n4) {
                float4 P = A1;
                int nxt = i + 5 * S;
                if (nxt < n4) A1 = p4[nxt];
                unsigned int code = (j + 1 < MAXJ)
                    ? (unsigned int)lds_codes[(j + 1) * BLK + threadIdx.x]
                    : ghm_code4(P, w4[i + S]);
                float4 O;
                O.x = wtab[code & 15u] * P.x;
                O.y = wtab[(code >> 4) & 15u] * P.y;
                O.z = wtab[(code >> 8) & 15u] * P.z;
                O.w = wtab[(code >> 12) & 15u] * P.w;
                ((float4*)out)[i + S] = O;
            }
            if (i + 2 * S < n4) {
                float4 P = A2;
                int nxt = i + 6 * S;
                if (nxt < n4) A2 = p4[nxt];
                unsigned int code = (j + 2 < MAXJ)
                    ? (unsigned int)lds_codes[(j + 2) * BLK + threadIdx.x]
                    : ghm_code4(P, w4[i + 2 * S]);
                float4 O;
                O.x = wtab[code & 15u] * P.x;
                O.y = wtab[(code >> 4) & 15u] * P.y;
                O.z = wtab[(code >> 8) & 15u] * P.z;
                O.w = wtab[(code >> 12) & 15u] * P.w;
                ((float4*)out)[i + 2 * S] = O;
            }
            if (i + 3 * S < n4) {
                float4 P = A3;
                int nxt = i + 7 * S;
                if (nxt < n4) A3 = p4[nxt];
                unsigned int code = (j + 3 < MAXJ)
                    ? (unsigned int)lds_codes[(j + 3) * BLK + threadIdx.x]
                    : ghm_code4(P, w4[i + 3 * S]);
                float4 O;
                O.x = wtab[code & 15u] * P.x;
                O.y = wtab[(code >> 4) & 15u] * P.y;
                O.z = wtab[(code >> 8) & 15u] * P.z;
                O.w = wtab[(code >> 12) & 15u] * P.w;
                ((float4*)out)[i + 3 * S] = O;
            }
            i += 4 * S; j += 4;
        }
        // scalar tail
        if (t0 == 0) {
            for (int t = n4 << 2; t < n; ++t) {
                int bin; bool lt;
                ghm_classify_fast(pred[t], bin, lt);
                bool ib = (lw[t] > 0.0f) && lt;
                out[t] = wtab[ib ? bin : 15] * pred[t];
            }
        }
    }
}

extern "C" void kernel_launch(void* const* d_in, const int* in_sizes, int n_in,
                              void* d_out, int out_size, void* d_ws, size_t ws_size,
                              hipStream_t stream)
{
    const float* pred = (const float*)d_in[0];
    // d_in[1] = target, unused by the math
    const float* lw   = (const float*)d_in[2];
    float* out        = (float*)d_out;
    const int n       = in_sizes[0];

    unsigned int* ws = (unsigned int*)d_ws;  // part[MAXG][16] + wtabg[16] + flag

    // Cooperative launch guarantees co-residency for the hand-rolled barrier.
    int dev = 0;
    hipGetDevice(&dev);
    int numCU = 0;
    hipDeviceGetAttribute(&numCU, hipDeviceAttributeMultiprocessorCount, dev);
    int maxB = 0;
    hipOccupancyMaxActiveBlocksPerMultiprocessor(&maxB, (const void*)ghm_fused, BLK, 0);
    long long G = (long long)maxB * (long long)numCU;
    if (G > 1024) G = 1024;   // 1024 x 256 thr: <=16 float4-groups/thread -> codes fit LDS
    if (G > MAXG) G = MAXG;
    if (G < 1) G = 1;

    void* args[] = { (void*)&pred, (void*)&lw, (void*)&ws, (void*)&out, (void*)&n };
    hipLaunchCooperativeKernel((const void*)ghm_fused, dim3((unsigned int)G),
                               dim3(BLK), args, 0, stream);
}